// Round 9
// baseline (92.315 us; speedup 1.0000x reference)
//
#include <hip/hip_runtime.h>
#include <math.h>

// NetVLAD fp32: N=32, D=512, K=64, P=1024
// ws = A(8MB) + wt(128KB) + ssqp(64KB) = 8.59 MB (proven-safe level).
// k0 : wt[d][k] transpose.
// k1a: logits GEMM + FUSED softmax (R7-proven inner loop). Epilogue now
//      writes A in [n][k][p] layout with per-64p-chunk XOR quad swizzle
//      stored_q = logical_q ^ (k>>3)  (for k2a's conflict-free reads).
// k2a: V GEMM, REBUILT: p is the vector dim for BOTH operands.
//      A chunks [64k][64p] and x chunks [64d][64p] both staged via LINEAR
//      global_load_lds (no reg transpose, no VALU LDS writes). Reads are
//      b128 along p with the XOR swizzle -> 8 distinct bank-quads per
//      instruction, 8-lane broadcast each (conflict-free). x source address
//      pre-swizzled (rule #21: LDS linear, source permuted). Lane tile
//      8k x 8d x 4p. Wave w owns p-quads {2w, 2w+1} per chunk.
//      s = sum_p a on the fly; 3-round lane-keyed tree (R7-proven);
//      -s*c; raw V -> d_out; partial ssq -> ssqp.
// k2c: intra + global L2 norm in place (proven).

namespace {

constexpr int NI   = 32;
constexpr int DIMC = 512;
constexpr int KCL  = 64;
constexpr int PIXN = 1024;
constexpr float EPSF = 1e-12f;

#define AS1 __attribute__((address_space(1)))
#define AS3 __attribute__((address_space(3)))

__device__ __forceinline__ void glds16(const float* g, float* l) {
  __builtin_amdgcn_global_load_lds((const AS1 void*)g, (AS3 void*)l, 16, 0, 0);
}

// ---------------------------------------------------------------------------
__global__ __launch_bounds__(256) void k0_wt(const float* __restrict__ w,
                                             float* __restrict__ wt) {
  const int i = blockIdx.x * 256 + threadIdx.x;   // 32768, wt[d][k]
  wt[i] = w[(size_t)(i & 63) * DIMC + (i >> 6)];
}

// ---------------------------------------------------------------------------
// k1a: 512 blocks = (n, pg 0..15 [64p]); 256 thr = 4 waves. (R7-proven body)
// ---------------------------------------------------------------------------
__global__ __launch_bounds__(256, 2) void k1a_logits(
    const float* __restrict__ x, const float* __restrict__ wt,
    const float* __restrict__ conv_b, float* __restrict__ A)
{
  __shared__ float smem[16384];       // xs[2][4096] | wl[2][4096]; scr=smem
  float* const xs0 = smem;            // [buf][dd*64 + p]
  float* const wl0 = smem + 8192;     // [buf][dd*64 + k]
  float* const scr = smem;            // 2 slots x 4096 (staging dead)

  const int tid = threadIdx.x;
  const int w  = __builtin_amdgcn_readfirstlane(tid >> 6);
  const int l  = tid & 63;
  const int lk = l & 7, ld = l >> 3;
  const int bid = blockIdx.x;
  const int xcd = bid & 7, rest = bid >> 3;   // n -> XCD n%8
  const int n  = xcd + ((rest & 3) << 3);
  const int pg = rest >> 2;                   // 0..15
  const int pb = pg << 6;

  const float* xn = x + (size_t)n * DIMC * PIXN + pb;

#pragma unroll
  for (int s = 0; s < 4; ++s) {
    const int i = s * 256 + tid;
    glds16(xn + (size_t)(i >> 4) * PIXN + ((i & 15) << 2), xs0 + (i << 2));
    glds16(wt + (i << 2), wl0 + (i << 2));
  }

  float acc[8][8];
#pragma unroll
  for (int i = 0; i < 8; ++i)
#pragma unroll
    for (int j = 0; j < 8; ++j) acc[i][j] = 0.0f;

  for (int ch = 0; ch < 8; ++ch) {    // 512 d in chunks of 64
    const int cur = ch & 1;
    __syncthreads();
    if (ch < 7) {
      const float* xc = xn + (size_t)((ch + 1) * 64) * PIXN;
      const float* wc = wt + (ch + 1) * 4096;
#pragma unroll
      for (int s = 0; s < 4; ++s) {
        const int i = s * 256 + tid;
        glds16(xc + (size_t)(i >> 4) * PIXN + ((i & 15) << 2),
               xs0 + (cur ^ 1) * 4096 + (i << 2));
        glds16(wc + (i << 2), wl0 + (cur ^ 1) * 4096 + (i << 2));
      }
    }
    const float* wr = wl0 + cur * 4096 + (w << 10) + (lk << 3);
    const float* xr = xs0 + cur * 4096 + (w << 10) + (ld << 3);
#pragma unroll 4
    for (int dd = 0; dd < 16; ++dd) {
      const float4 wa = *reinterpret_cast<const float4*>(wr + (dd << 6));
      const float4 wb = *reinterpret_cast<const float4*>(wr + (dd << 6) + 4);
      const float4 xa = *reinterpret_cast<const float4*>(xr + (dd << 6));
      const float4 xb = *reinterpret_cast<const float4*>(xr + (dd << 6) + 4);
      const float wv[8] = {wa.x, wa.y, wa.z, wa.w, wb.x, wb.y, wb.z, wb.w};
      const float xv[8] = {xa.x, xa.y, xa.z, xa.w, xb.x, xb.y, xb.z, xb.w};
#pragma unroll
      for (int i = 0; i < 8; ++i)
#pragma unroll
        for (int j = 0; j < 8; ++j)
          acc[i][j] = fmaf(wv[i], xv[j], acc[i][j]);
    }
  }
  __syncthreads();

#define TST(RB)                                                              \
  do {                                                                       \
    _Pragma("unroll") for (int i = 0; i < 8; ++i) {                          \
      *reinterpret_cast<float4*>((RB) + ((2 * i) << 8) + (l << 2)) =         \
          make_float4(acc[i][0], acc[i][1], acc[i][2], acc[i][3]);           \
      *reinterpret_cast<float4*>((RB) + ((2 * i + 1) << 8) + (l << 2)) =     \
          make_float4(acc[i][4], acc[i][5], acc[i][6], acc[i][7]);           \
    }                                                                        \
  } while (0)
#define TADD(RB)                                                             \
  do {                                                                       \
    _Pragma("unroll") for (int i = 0; i < 8; ++i) {                          \
      const float4 t0 = *reinterpret_cast<const float4*>(                    \
          (RB) + ((2 * i) << 8) + (l << 2));                                 \
      const float4 t1 = *reinterpret_cast<const float4*>(                    \
          (RB) + ((2 * i + 1) << 8) + (l << 2));                             \
      acc[i][0] += t0.x; acc[i][1] += t0.y; acc[i][2] += t0.z;               \
      acc[i][3] += t0.w; acc[i][4] += t1.x; acc[i][5] += t1.y;               \
      acc[i][6] += t1.z; acc[i][7] += t1.w;                                  \
    }                                                                        \
  } while (0)

  if (w == 1) TST(scr);
  if (w == 3) TST(scr + 4096);
  __syncthreads();
  if (w == 0) TADD(scr);
  if (w == 2) TADD(scr + 4096);
  __syncthreads();
  if (w == 2) TST(scr);
  __syncthreads();

  if (w == 0) {
    TADD(scr);
    const float4 b0 = *reinterpret_cast<const float4*>(conv_b + (lk << 3));
    const float4 b1 = *reinterpret_cast<const float4*>(conv_b + (lk << 3) + 4);
    const float bv[8] = {b0.x, b0.y, b0.z, b0.w, b1.x, b1.y, b1.z, b1.w};
#pragma unroll
    for (int i = 0; i < 8; ++i)
#pragma unroll
      for (int j = 0; j < 8; ++j) acc[i][j] += bv[i];
    float m[8], S[8];
#pragma unroll
    for (int j = 0; j < 8; ++j) {
      m[j] = acc[0][j];
#pragma unroll
      for (int i = 1; i < 8; ++i) m[j] = fmaxf(m[j], acc[i][j]);
      m[j] = fmaxf(m[j], __shfl_xor(m[j], 1, 64));
      m[j] = fmaxf(m[j], __shfl_xor(m[j], 2, 64));
      m[j] = fmaxf(m[j], __shfl_xor(m[j], 4, 64));
      S[j] = 0.0f;
#pragma unroll
      for (int i = 0; i < 8; ++i) {
        acc[i][j] = __expf(acc[i][j] - m[j]);
        S[j] += acc[i][j];
      }
      S[j] += __shfl_xor(S[j], 1, 64);
      S[j] += __shfl_xor(S[j], 2, 64);
      S[j] += __shfl_xor(S[j], 4, 64);
      S[j] = 1.0f / S[j];
    }
    // write A[n][k][p], p-quad XOR-swizzled within this 64p chunk:
    // logical quads L0=2ld (acc[i][0..3]), L1=2ld+1 (acc[i][4..7]);
    // stored(L) = L ^ lk -> adjacent pair at bq = (2ld ^ lk) & ~1.
    const int bq = ((ld << 1) ^ lk) & ~1;
#pragma unroll
    for (int i = 0; i < 8; ++i) {
      const float4 lo = make_float4(acc[i][0] * S[0], acc[i][1] * S[1],
                                    acc[i][2] * S[2], acc[i][3] * S[3]);
      const float4 hi = make_float4(acc[i][4] * S[4], acc[i][5] * S[5],
                                    acc[i][6] * S[6], acc[i][7] * S[7]);
      float* arow = A + ((size_t)n * KCL + (lk << 3) + i) * PIXN + pb + (bq << 2);
      if (lk & 1) {
        *reinterpret_cast<float4*>(arow)     = hi;
        *reinterpret_cast<float4*>(arow + 4) = lo;
      } else {
        *reinterpret_cast<float4*>(arow)     = lo;
        *reinterpret_cast<float4*>(arow + 4) = hi;
      }
    }
  }
#undef TST
#undef TADD
}

// ---------------------------------------------------------------------------
// k2a: 256 blocks = (n, dt 0..7 [64d]); 512 thr = 8 waves (2/SIMD).
// A[64k][64p] (glds linear, pre-swizzled by k1a) + x[64d][64p] (glds linear,
// source-address swizzled). Lane (lk,ld): k=8lk+i, d=d0+8ld+jd. Wave w:
// p-quads {2w,2w+1}. Reads: b128 at row*64 + 4*(pq^rowhi) — conflict-free.
// ---------------------------------------------------------------------------
__global__ __launch_bounds__(512, 2) void k2a_vlad(
    const float* __restrict__ x, const float* __restrict__ A,
    const float* __restrict__ cent, float* __restrict__ out,
    float* __restrict__ ssqp)
{
  __shared__ float smem[18432];   // aL[2][4096] | xL[2][4096]; scr=smem (union)
  float* const aL0 = smem;
  float* const xL0 = smem + 8192;
  float* const scr = smem;

  const int tid = threadIdx.x;
  const int w  = __builtin_amdgcn_readfirstlane(tid >> 6);
  const int l  = tid & 63;
  const int lk = l & 7, ld = l >> 3;
  const int bid = blockIdx.x;
  const int xcd = bid & 7, rest = bid >> 3;
  const int n  = xcd + ((rest & 3) << 3);
  const int dt = rest >> 2;
  const int d0 = dt << 6;

  const float* an = A + (size_t)n * (KCL * PIXN);
  const float* xn = x + ((size_t)n * DIMC + d0) * PIXN;
  const int i0 = tid, i1 = tid + 512;
  // x source swizzle: stored slot (row=i>>4, qs=i&15) <- logical q = qs^(row>>3)
  const int xq0 = ((i0 & 15) ^ (i0 >> 7)) << 2;
  const int xq1 = (((i1 & 15) ^ (i1 >> 7)) & 15) << 2;

  // prologue: chunk 0 (A and x, all linear glds)
  glds16(an + (size_t)(i0 >> 4) * PIXN + ((i0 & 15) << 2), aL0 + (i0 << 2));
  glds16(an + (size_t)(i1 >> 4) * PIXN + ((i1 & 15) << 2), aL0 + (i1 << 2));
  glds16(xn + (size_t)(i0 >> 4) * PIXN + xq0, xL0 + (i0 << 2));
  glds16(xn + (size_t)(i1 >> 4) * PIXN + xq1, xL0 + (i1 << 2));

  float acc[8][8], sacc[8];
#pragma unroll
  for (int i = 0; i < 8; ++i) {
    sacc[i] = 0.0f;
#pragma unroll
    for (int j = 0; j < 8; ++j) acc[i][j] = 0.0f;
  }
  __syncthreads();

  for (int ch = 0; ch < 16; ++ch) {   // P in chunks of 64; wave does 2 pq
    const int cur = ch & 1;
    const float* aLc = aL0 + cur * 4096;
    const float* xLc = xL0 + cur * 4096;
    if (ch < 15) {                    // prefetch ch+1 (lands during compute)
      const int c2 = (ch + 1) * 64;
      float* aLn = aL0 + (cur ^ 1) * 4096;
      float* xLn = xL0 + (cur ^ 1) * 4096;
      glds16(an + (size_t)(i0 >> 4) * PIXN + c2 + ((i0 & 15) << 2), aLn + (i0 << 2));
      glds16(an + (size_t)(i1 >> 4) * PIXN + c2 + ((i1 & 15) << 2), aLn + (i1 << 2));
      glds16(xn + (size_t)(i0 >> 4) * PIXN + c2 + xq0, xLn + (i0 << 2));
      glds16(xn + (size_t)(i1 >> 4) * PIXN + c2 + xq1, xLn + (i1 << 2));
    }
#pragma unroll
    for (int q = 0; q < 2; ++q) {
      const int pq = (w << 1) + q;
      float4 af[8], xf[8];
#pragma unroll
      for (int i = 0; i < 8; ++i)
        af[i] = *reinterpret_cast<const float4*>(
            aLc + (((lk << 3) + i) << 6) + ((pq ^ lk) << 2));
#pragma unroll
      for (int jd = 0; jd < 8; ++jd)
        xf[jd] = *reinterpret_cast<const float4*>(
            xLc + (((ld << 3) + jd) << 6) + ((pq ^ ld) << 2));
#pragma unroll
      for (int i = 0; i < 8; ++i) {
        sacc[i] += ((af[i].x + af[i].y) + af[i].z) + af[i].w;
#pragma unroll
        for (int jd = 0; jd < 8; ++jd) {
          acc[i][jd] = fmaf(af[i].x, xf[jd].x, acc[i][jd]);
          acc[i][jd] = fmaf(af[i].y, xf[jd].y, acc[i][jd]);
          acc[i][jd] = fmaf(af[i].z, xf[jd].z, acc[i][jd]);
          acc[i][jd] = fmaf(af[i].w, xf[jd].w, acc[i][jd]);
        }
      }
    }
    __syncthreads();
  }

  // 3-round lane-keyed reduction: 18 quads/lane (16 acc + 2 sacc)
#define TST(RB)                                                              \
  do {                                                                       \
    _Pragma("unroll") for (int i = 0; i < 8; ++i) {                          \
      *reinterpret_cast<float4*>((RB) + ((2 * i) << 8) + (l << 2)) =         \
          make_float4(acc[i][0], acc[i][1], acc[i][2], acc[i][3]);           \
      *reinterpret_cast<float4*>((RB) + ((2 * i + 1) << 8) + (l << 2)) =     \
          make_float4(acc[i][4], acc[i][5], acc[i][6], acc[i][7]);           \
    }                                                                        \
    *reinterpret_cast<float4*>((RB) + (16 << 8) + (l << 2)) =                \
        make_float4(sacc[0], sacc[1], sacc[2], sacc[3]);                     \
    *reinterpret_cast<float4*>((RB) + (17 << 8) + (l << 2)) =                \
        make_float4(sacc[4], sacc[5], sacc[6], sacc[7]);                     \
  } while (0)
#define TADD(RB)                                                             \
  do {                                                                       \
    _Pragma("unroll") for (int i = 0; i < 8; ++i) {                          \
      const float4 t0 = *reinterpret_cast<const float4*>(                    \
          (RB) + ((2 * i) << 8) + (l << 2));                                 \
      const float4 t1 = *reinterpret_cast<const float4*>(                    \
          (RB) + ((2 * i + 1) << 8) + (l << 2));                             \
      acc[i][0] += t0.x; acc[i][1] += t0.y; acc[i][2] += t0.z;               \
      acc[i][3] += t0.w; acc[i][4] += t1.x; acc[i][5] += t1.y;               \
      acc[i][6] += t1.z; acc[i][7] += t1.w;                                  \
    }                                                                        \
    const float4 s0 = *reinterpret_cast<const float4*>(                      \
        (RB) + (16 << 8) + (l << 2));                                        \
    const float4 s1 = *reinterpret_cast<const float4*>(                      \
        (RB) + (17 << 8) + (l << 2));                                        \
    sacc[0] += s0.x; sacc[1] += s0.y; sacc[2] += s0.z; sacc[3] += s0.w;      \
    sacc[4] += s1.x; sacc[5] += s1.y; sacc[6] += s1.z; sacc[7] += s1.w;      \
  } while (0)

  if (w >= 4) TST(scr + (w - 4) * 4608);
  __syncthreads();
  if (w < 4) TADD(scr + w * 4608);
  __syncthreads();
  if (w == 2) TST(scr);
  if (w == 3) TST(scr + 4608);
  __syncthreads();
  if (w < 2) TADD(scr + w * 4608);
  __syncthreads();
  if (w == 1) TST(scr);
  __syncthreads();

  if (w == 0) {
    TADD(scr);   // final, deterministic fixed tree
#pragma unroll
    for (int i = 0; i < 8; ++i) {
      const int k = (lk << 3) + i;
      const float s = sacc[i];
      const float* cp = cent + (size_t)k * DIMC + d0 + (ld << 3);
      const float4 c0 = *reinterpret_cast<const float4*>(cp);
      const float4 c1 = *reinterpret_cast<const float4*>(cp + 4);
      float r[8];
      r[0] = acc[i][0] - s * c0.x; r[1] = acc[i][1] - s * c0.y;
      r[2] = acc[i][2] - s * c0.z; r[3] = acc[i][3] - s * c0.w;
      r[4] = acc[i][4] - s * c1.x; r[5] = acc[i][5] - s * c1.y;
      r[6] = acc[i][6] - s * c1.z; r[7] = acc[i][7] - s * c1.w;
      float* op = out + ((size_t)n * KCL + k) * DIMC + d0 + (ld << 3);
      *reinterpret_cast<float4*>(op)     = make_float4(r[0], r[1], r[2], r[3]);
      *reinterpret_cast<float4*>(op + 4) = make_float4(r[4], r[5], r[6], r[7]);
      float q = 0.0f;
#pragma unroll
      for (int j = 0; j < 8; ++j) q = fmaf(r[j], r[j], q);
      q += __shfl_xor(q, 8, 64);
      q += __shfl_xor(q, 16, 64);
      q += __shfl_xor(q, 32, 64);
      if (ld == 0) ssqp[((size_t)n * KCL + k) * 8 + dt] = q;
    }
  }
#undef TST
#undef TADD
}

// ---------------------------------------------------------------------------
// k2c: 256 blocks = (n, kc 0..7); intra + global norm in place (proven).
// ---------------------------------------------------------------------------
__global__ __launch_bounds__(256) void k2c_norm(
    const float* __restrict__ ssqp, float* __restrict__ out)
{
  __shared__ float invs[64];
  __shared__ float gsh;
  const int tid = threadIdx.x;
  const int n  = blockIdx.x >> 3;
  const int kc = blockIdx.x & 7;
  if (tid < 64) {
    float ssq = 0.0f;
#pragma unroll
    for (int dt = 0; dt < 8; ++dt)
      ssq += ssqp[((size_t)n * KCL + tid) * 8 + dt];   // fixed order
    const float inv = 1.0f / fmaxf(sqrtf(ssq), EPSF);
    invs[tid] = inv;
    float rqv = ssq * inv * inv;
#pragma unroll
    for (int off = 32; off > 0; off >>= 1) rqv += __shfl_xor(rqv, off, 64);
    if (tid == 0) gsh = 1.0f / fmaxf(sqrtf(rqv), EPSF);
  }
  __syncthreads();
  const float sc = invs[(kc << 3) + (tid >> 5)] * gsh;
  float* o = out + ((size_t)n * KCL + (kc << 3)) * DIMC + tid * 16;
#pragma unroll
  for (int q = 0; q < 4; ++q) {
    float4 v = *reinterpret_cast<float4*>(o + (q << 2));
    v.x *= sc; v.y *= sc; v.z *= sc; v.w *= sc;
    *reinterpret_cast<float4*>(o + (q << 2)) = v;
  }
}

}  // namespace

extern "C" void kernel_launch(void* const* d_in, const int* in_sizes, int n_in,
                              void* d_out, int out_size, void* d_ws, size_t ws_size,
                              hipStream_t stream) {
  (void)in_sizes; (void)n_in; (void)out_size; (void)ws_size;
  const float* x      = (const float*)d_in[0];
  const float* cent   = (const float*)d_in[1];
  const float* conv_w = (const float*)d_in[2];
  const float* conv_b = (const float*)d_in[3];
  float* out = (float*)d_out;
  float* ws  = (float*)d_ws;

  // ws (floats): A 2097152 | wt 32768 | ssqp 16384  = 8.59 MB (proven-safe)
  float* A    = ws;
  float* wt   = A + (size_t)NI * PIXN * KCL;
  float* ssqp = wt + 32768;

  k0_wt     <<<128, 256, 0, stream>>>(conv_w, wt);
  k1a_logits<<<512, 256, 0, stream>>>(x, wt, conv_b, A);
  k2a_vlad  <<<256, 512, 0, stream>>>(x, A, cent, out, ssqp);
  k2c_norm  <<<256, 256, 0, stream>>>(ssqp, out);
}